// Round 1
// baseline (323.101 us; speedup 1.0000x reference)
//
#include <hip/hip_runtime.h>
#include <math.h>

// CoherentLoss: N=16384 trajectories, grid M ~= 2401 points.
// Phases: prep (bins/centers/prefactor) -> presence scan (unique ranks) ->
// scatter-add into compact bins -> per-trajectory trapz overlap gt + loss.

#define PRES_SIZE 65536
#define PRES_OFF  32768

__global__ void prep_kernel(const float* __restrict__ f_re, const float* __restrict__ f_im,
                            const float* __restrict__ q_re, const float* __restrict__ q_im,
                            const float* __restrict__ p_re, const float* __restrict__ p_im,
                            float* __restrict__ qc, float* __restrict__ pc,
                            float* __restrict__ vre, float* __restrict__ vim,
                            int* __restrict__ bins, int* __restrict__ pres, int n)
{
    int i = blockIdx.x * blockDim.x + threadIdx.x;
    if (i >= n) return;
    const float norm = 0.8932438417380023f; // (2/pi)^0.25
    float qi = q_im[i], pr = p_re[i];
    // qf = q_re - p_im/(2g), pf = 2g*q_im + p_re, g = 1  (exact pow2 ops)
    float qf = q_re[i] - 0.5f * p_im[i];
    float pf = 2.0f * qi + pr;
    // dq = 0.125, dp = 0.15625 (both exact binary) -- match reference op order
    float qb = floorf((qf - (-8.0f)) / 0.125f);
    float pb = floorf((pf - (-10.0f)) / 0.15625f);
    int b = (int)(qb * 128.0f + pb);
    bins[i] = b;
    int pidx = b + PRES_OFF;
    pidx = min(max(pidx, 0), PRES_SIZE - 1);
    pres[pidx] = 1;                 // plain store, same-value race is benign
    qc[i] = (qb + 0.5f) * 0.125f + (-8.0f);
    pc[i] = (pb + 0.5f) * 0.15625f + (-10.0f);
    // pref = norm * exp(q_im^2 + i*p_re*q_im), clamp re/im to [-100,100]
    float ea = norm * expf(qi * qi);
    float s, c;
    __sincosf(pr * qi, &s, &c);
    float prr = fminf(fmaxf(ea * c, -100.0f), 100.0f);
    float pri = fminf(fmaxf(ea * s, -100.0f), 100.0f);
    float fr = f_re[i], fi = f_im[i];
    vre[i] = prr * fr - pri * fi;   // vals = pref * factors
    vim[i] = prr * fi + pri * fr;
}

// trapz weight * psi * norm, folded once per grid point
__global__ void wpsi_kernel(const float* __restrict__ x, const float* __restrict__ psi,
                            float* __restrict__ wpsi, int M)
{
    int m = blockIdx.x * blockDim.x + threadIdx.x;
    if (m >= M) return;
    float w;
    if (m == 0)            w = 0.5f * (x[1] - x[0]);
    else if (m == M - 1)   w = 0.5f * (x[M - 1] - x[M - 2]);
    else                   w = 0.5f * (x[m + 1] - x[m - 1]);
    wpsi[m] = w * psi[m] * 0.8932438417380023f;
}

// exclusive prefix sum over presence bitmap -> compact bin id (unique rank)
__global__ void scan_kernel(int* __restrict__ pres)
{
    __shared__ int partials[1024];
    int t = threadIdx.x;
    int base = t * 64;
    int s = 0;
    for (int k = 0; k < 64; k++) s += pres[base + k];
    partials[t] = s;
    __syncthreads();
    for (int off = 1; off < 1024; off <<= 1) {
        int v = (t >= off) ? partials[t - off] : 0;
        __syncthreads();
        partials[t] += v;
        __syncthreads();
    }
    int run = (t == 0) ? 0 : partials[t - 1];  // exclusive prefix at chunk start
    for (int k = 0; k < 64; k++) {
        int v = pres[base + k];
        pres[base + k] = run;
        run += v;
    }
}

__global__ void scatter_kernel(const int* __restrict__ bins, const int* __restrict__ ranks,
                               const float* __restrict__ vre, const float* __restrict__ vim,
                               float* __restrict__ bre, float* __restrict__ bim, int n)
{
    int i = blockIdx.x * blockDim.x + threadIdx.x;
    if (i >= n) return;
    int pidx = min(max(bins[i] + PRES_OFF, 0), PRES_SIZE - 1);
    int cid = ranks[pidx];          // rank among sorted unique bins, < n
    atomicAdd(&bre[cid], vre[i]);
    atomicAdd(&bim[cid], vim[i]);
}

// one block per trajectory: gt[n] = sum_m wpsi[m]*exp(-dxq^2)*(cos - i sin)(pc*dxq)
// then loss += |binned[n] - gt[n]|^2
__global__ void gt_loss_kernel(const float* __restrict__ x, const float* __restrict__ wpsi,
                               const float* __restrict__ qc, const float* __restrict__ pc,
                               const float* __restrict__ bre, const float* __restrict__ bim,
                               float* __restrict__ loss, int M)
{
    int nidx = blockIdx.x;
    float qcn = qc[nidx], pcn = pc[nidx];
    float sre = 0.0f, sim = 0.0f;
    for (int m = threadIdx.x; m < M; m += 256) {
        float dxq = x[m] - qcn;
        float e = __expf(-dxq * dxq) * wpsi[m];
        float s, c;
        __sincosf(pcn * dxq, &s, &c);
        sre = fmaf(e, c, sre);
        sim = fmaf(-e, s, sim);
    }
#pragma unroll
    for (int off = 32; off > 0; off >>= 1) {
        sre += __shfl_down(sre, off);
        sim += __shfl_down(sim, off);
    }
    __shared__ float lre[4], lim[4];
    int wv = threadIdx.x >> 6, ln = threadIdx.x & 63;
    if (ln == 0) { lre[wv] = sre; lim[wv] = sim; }
    __syncthreads();
    if (threadIdx.x == 0) {
        float tre = lre[0] + lre[1] + lre[2] + lre[3];
        float tim = lim[0] + lim[1] + lim[2] + lim[3];
        float dre = bre[nidx] - tre;
        float dim = bim[nidx] - tim;
        atomicAdd(loss, dre * dre + dim * dim);
    }
}

__global__ void finalize_kernel(const float* __restrict__ loss, float* __restrict__ out)
{
    out[0] = sqrtf(loss[0]);
}

extern "C" void kernel_launch(void* const* d_in, const int* in_sizes, int n_in,
                              void* d_out, int out_size, void* d_ws, size_t ws_size,
                              hipStream_t stream)
{
    const float* f_re = (const float*)d_in[0];
    const float* f_im = (const float*)d_in[1];
    const float* q_re = (const float*)d_in[2];
    const float* q_im = (const float*)d_in[3];
    const float* p_re = (const float*)d_in[4];
    const float* p_im = (const float*)d_in[5];
    const float* x    = (const float*)d_in[6];
    const float* psi  = (const float*)d_in[7];
    int n = in_sizes[0];   // 16384
    int M = in_sizes[6];   // ~2401

    // workspace layout (all 4-byte elems)
    float* wsf  = (float*)d_ws;
    float* qc   = wsf;
    float* pc   = qc + n;
    float* vre  = pc + n;
    float* vim  = vre + n;
    int*   bins = (int*)(vim + n);
    float* wpsi = (float*)(bins + n);
    // zeroed region: bre | bim | pres | loss (contiguous)
    float* bre  = wpsi + 4096;
    float* bim  = bre + n;
    int*   pres = (int*)(bim + n);
    float* loss = (float*)(pres + PRES_SIZE);

    hipMemsetAsync(bre, 0, (size_t)(2 * n + PRES_SIZE + 1) * sizeof(float), stream);

    prep_kernel<<<(n + 255) / 256, 256, 0, stream>>>(f_re, f_im, q_re, q_im, p_re, p_im,
                                                     qc, pc, vre, vim, bins, pres, n);
    wpsi_kernel<<<(M + 255) / 256, 256, 0, stream>>>(x, psi, wpsi, M);
    scan_kernel<<<1, 1024, 0, stream>>>(pres);
    scatter_kernel<<<(n + 255) / 256, 256, 0, stream>>>(bins, pres, vre, vim, bre, bim, n);
    gt_loss_kernel<<<n, 256, 0, stream>>>(x, wpsi, qc, pc, bre, bim, loss, M);
    finalize_kernel<<<1, 1, 0, stream>>>(loss, (float*)d_out);
}

// Round 2
// 123.377 us; speedup vs baseline: 2.6188x; 2.6188x over previous
//
#include <hip/hip_runtime.h>
#include <math.h>

// CoherentLoss: N=16384 trajectories, grid M ~= 2401 points.
// prep (bins/centers/prefactor) -> bitmask presence + popcount scan (unique
// ranks) -> scatter-add into compact bins -> gt via lane-per-trajectory,
// wave-uniform m loop (scalar-broadcast x/wpsi), M chunked over blockIdx.y
// with atomic partial accumulation -> loss reduce -> sqrt.

#define PRES_BITS  65536
#define PRES_WORDS 1024          // 65536 bins / 64 bits
#define PRES_OFF   32768
#define CHUNKS     16

__global__ void prep_kernel(const float* __restrict__ f_re, const float* __restrict__ f_im,
                            const float* __restrict__ q_re, const float* __restrict__ q_im,
                            const float* __restrict__ p_re, const float* __restrict__ p_im,
                            float* __restrict__ qc, float* __restrict__ pc,
                            float* __restrict__ vre, float* __restrict__ vim,
                            int* __restrict__ bins, unsigned long long* __restrict__ pres, int n)
{
    int i = blockIdx.x * blockDim.x + threadIdx.x;
    if (i >= n) return;
    const float norm = 0.8932438417380023f; // (2/pi)^0.25
    float qi = q_im[i], pr = p_re[i];
    float qf = q_re[i] - 0.5f * p_im[i];     // g = 1, exact pow2 ops
    float pf = 2.0f * qi + pr;
    float qb = floorf((qf - (-8.0f)) / 0.125f);   // dq = 0.125 exact
    float pb = floorf((pf - (-10.0f)) / 0.15625f); // dp = 0.15625 exact
    int b = (int)(qb * 128.0f + pb);
    bins[i] = b;
    int pidx = min(max(b + PRES_OFF, 0), PRES_BITS - 1);
    atomicOr(&pres[pidx >> 6], 1ull << (pidx & 63));
    qc[i] = (qb + 0.5f) * 0.125f + (-8.0f);
    pc[i] = (pb + 0.5f) * 0.15625f + (-10.0f);
    float ea = norm * expf(qi * qi);
    float s, c;
    __sincosf(pr * qi, &s, &c);
    float prr = fminf(fmaxf(ea * c, -100.0f), 100.0f);
    float pri = fminf(fmaxf(ea * s, -100.0f), 100.0f);
    float fr = f_re[i], fi = f_im[i];
    vre[i] = prr * fr - pri * fi;   // vals = pref * factors
    vim[i] = prr * fi + pri * fr;
}

// trapz weight * psi * norm, folded once per grid point
__global__ void wpsi_kernel(const float* __restrict__ x, const float* __restrict__ psi,
                            float* __restrict__ wpsi, int M)
{
    int m = blockIdx.x * blockDim.x + threadIdx.x;
    if (m >= M) return;
    float w;
    if (m == 0)            w = 0.5f * (x[1] - x[0]);
    else if (m == M - 1)   w = 0.5f * (x[M - 1] - x[M - 2]);
    else                   w = 0.5f * (x[m + 1] - x[m - 1]);
    wpsi[m] = w * psi[m] * 0.8932438417380023f;
}

// exclusive prefix over per-word popcounts -> base rank per 64-bin word
__global__ void scan_kernel(const unsigned long long* __restrict__ pres, int* __restrict__ base)
{
    __shared__ int partials[PRES_WORDS];
    int t = threadIdx.x;
    int c = __popcll(pres[t]);
    partials[t] = c;
    __syncthreads();
    for (int off = 1; off < PRES_WORDS; off <<= 1) {
        int v = (t >= off) ? partials[t - off] : 0;
        __syncthreads();
        partials[t] += v;
        __syncthreads();
    }
    base[t] = partials[t] - c;   // exclusive prefix
}

__global__ void scatter_kernel(const int* __restrict__ bins,
                               const unsigned long long* __restrict__ pres,
                               const int* __restrict__ base,
                               const float* __restrict__ vre, const float* __restrict__ vim,
                               float* __restrict__ bre, float* __restrict__ bim, int n)
{
    int i = blockIdx.x * blockDim.x + threadIdx.x;
    if (i >= n) return;
    int pidx = min(max(bins[i] + PRES_OFF, 0), PRES_BITS - 1);
    int w = pidx >> 6, bit = pidx & 63;
    unsigned long long below = pres[w] & ((bit == 0) ? 0ull : (~0ull >> (64 - bit)));
    int cid = base[w] + __popcll(below);   // rank among sorted unique bins
    atomicAdd(&bre[cid], vre[i]);
    atomicAdd(&bim[cid], vim[i]);
}

// lane-per-trajectory: m is wave-uniform -> x[m], wpsi[m] are scalar broadcasts.
// M split into CHUNKS slices over blockIdx.y; partial gt accumulated atomically.
__global__ void gt_kernel(const float* __restrict__ x, const float* __restrict__ wpsi,
                          const float* __restrict__ qc, const float* __restrict__ pc,
                          float* __restrict__ gre, float* __restrict__ gim,
                          int n, int M, int chunk)
{
    int t = blockIdx.x * blockDim.x + threadIdx.x;
    if (t >= n) return;
    float qcn = qc[t], pcn = pc[t];
    int m0 = blockIdx.y * chunk;
    int m1 = min(m0 + chunk, M);
    float sre = 0.0f, sim = 0.0f;
#pragma unroll 4
    for (int m = m0; m < m1; m++) {
        float xm = x[m], wm = wpsi[m];     // wave-uniform -> s_load broadcast
        float dxq = xm - qcn;
        float e = __expf(-dxq * dxq) * wm;
        float s, c;
        __sincosf(pcn * dxq, &s, &c);
        sre = fmaf(e, c, sre);
        sim = fmaf(-e, s, sim);
    }
    atomicAdd(&gre[t], sre);
    atomicAdd(&gim[t], sim);
}

__global__ void loss_kernel(const float* __restrict__ gre, const float* __restrict__ gim,
                            const float* __restrict__ bre, const float* __restrict__ bim,
                            float* __restrict__ loss, int n)
{
    int t = blockIdx.x * blockDim.x + threadIdx.x;
    float v = 0.0f;
    if (t < n) {
        float dre = bre[t] - gre[t];
        float dim = bim[t] - gim[t];
        v = dre * dre + dim * dim;
    }
#pragma unroll
    for (int off = 32; off > 0; off >>= 1) v += __shfl_down(v, off);
    __shared__ float l[4];
    int wv = threadIdx.x >> 6, ln = threadIdx.x & 63;
    if (ln == 0) l[wv] = v;
    __syncthreads();
    if (threadIdx.x == 0)
        atomicAdd(loss, l[0] + l[1] + l[2] + l[3]);
}

__global__ void finalize_kernel(const float* __restrict__ loss, float* __restrict__ out)
{
    out[0] = sqrtf(loss[0]);
}

extern "C" void kernel_launch(void* const* d_in, const int* in_sizes, int n_in,
                              void* d_out, int out_size, void* d_ws, size_t ws_size,
                              hipStream_t stream)
{
    const float* f_re = (const float*)d_in[0];
    const float* f_im = (const float*)d_in[1];
    const float* q_re = (const float*)d_in[2];
    const float* q_im = (const float*)d_in[3];
    const float* p_re = (const float*)d_in[4];
    const float* p_im = (const float*)d_in[5];
    const float* x    = (const float*)d_in[6];
    const float* psi  = (const float*)d_in[7];
    int n = in_sizes[0];   // 16384
    int M = in_sizes[6];   // ~2401

    // workspace layout (4-byte elems unless noted)
    float* wsf  = (float*)d_ws;
    float* qc   = wsf;
    float* pc   = qc + n;
    float* vre  = pc + n;
    float* vim  = vre + n;
    int*   bins = (int*)(vim + n);
    float* wpsi = (float*)(bins + n);
    int*   base = (int*)(wpsi + 4096);
    // zeroed region: bre | bim | gre | gim | presmask | loss (contiguous)
    float* bre  = (float*)(base + PRES_WORDS);
    float* bim  = bre + n;
    float* gre  = bim + n;
    float* gim  = gre + n;
    unsigned long long* pres = (unsigned long long*)(gim + n);
    float* loss = (float*)(pres + PRES_WORDS);

    hipMemsetAsync(bre, 0, (size_t)(4 * n + 2 * PRES_WORDS + 1) * sizeof(float), stream);

    int chunk = (M + CHUNKS - 1) / CHUNKS;
    prep_kernel<<<(n + 255) / 256, 256, 0, stream>>>(f_re, f_im, q_re, q_im, p_re, p_im,
                                                     qc, pc, vre, vim, bins, pres, n);
    wpsi_kernel<<<(M + 255) / 256, 256, 0, stream>>>(x, psi, wpsi, M);
    scan_kernel<<<1, PRES_WORDS, 0, stream>>>(pres, base);
    scatter_kernel<<<(n + 255) / 256, 256, 0, stream>>>(bins, pres, base, vre, vim, bre, bim, n);
    gt_kernel<<<dim3((n + 255) / 256, CHUNKS), 256, 0, stream>>>(x, wpsi, qc, pc, gre, gim,
                                                                 n, M, chunk);
    loss_kernel<<<(n + 255) / 256, 256, 0, stream>>>(gre, gim, bre, bim, loss, n);
    finalize_kernel<<<1, 1, 0, stream>>>(loss, (float*)d_out);
}

// Round 3
// 118.074 us; speedup vs baseline: 2.7364x; 1.0449x over previous
//
#include <hip/hip_runtime.h>
#include <math.h>

// CoherentLoss: N=16384 trajectories, grid M ~= 2401 points (x uniform, h=0.01).
// 5 dispatches: memset(8.2KB) -> prep(+wpsi+zero binned) -> scatter(+inline
// 1-wave popcount scan) -> gt (windowed |dxq|<=4.5, chunked, non-atomic
// partials) -> loss reduce (+last-block sqrt finalize).

#define PRES_WORDS 1024          // 65536 bins / 64 bits
#define PRES_BITS  65536
#define PRES_OFF   32768
#define CHUNKS     16
#define WINR       4.5f          // exp(-4.5^2) = 1.6e-9 -> truncation negligible

__global__ void prep_kernel(const float* __restrict__ f_re, const float* __restrict__ f_im,
                            const float* __restrict__ q_re, const float* __restrict__ q_im,
                            const float* __restrict__ p_re, const float* __restrict__ p_im,
                            const float* __restrict__ x, const float* __restrict__ psi,
                            float* __restrict__ qc, float* __restrict__ pc,
                            float* __restrict__ vre, float* __restrict__ vim,
                            int* __restrict__ bins, unsigned long long* __restrict__ pres,
                            float* __restrict__ bre, float* __restrict__ bim,
                            float2* __restrict__ xw, int n, int M)
{
    int i = blockIdx.x * blockDim.x + threadIdx.x;
    if (i >= n) return;
    bre[i] = 0.0f; bim[i] = 0.0f;          // zero binned accumulators (pre-scatter)
    if (i < M) {                            // folded wpsi: trapz weight * psi * norm
        float w;
        if (i == 0)          w = 0.5f * (x[1] - x[0]);
        else if (i == M - 1) w = 0.5f * (x[M - 1] - x[M - 2]);
        else                 w = 0.5f * (x[i + 1] - x[i - 1]);
        xw[i] = make_float2(x[i], w * psi[i] * 0.8932438417380023f);
    }
    const float norm = 0.8932438417380023f; // (2/pi)^0.25
    float qi = q_im[i], pr = p_re[i];
    float qf = q_re[i] - 0.5f * p_im[i];    // g = 1, exact pow2 ops
    float pf = 2.0f * qi + pr;
    float qb = floorf((qf - (-8.0f)) / 0.125f);    // dq = 0.125 exact
    float pb = floorf((pf - (-10.0f)) / 0.15625f); // dp = 0.15625 exact
    int b = (int)(qb * 128.0f + pb);
    bins[i] = b;
    int pidx = min(max(b + PRES_OFF, 0), PRES_BITS - 1);
    atomicOr(&pres[pidx >> 6], 1ull << (pidx & 63));
    qc[i] = (qb + 0.5f) * 0.125f + (-8.0f);
    pc[i] = (pb + 0.5f) * 0.15625f + (-10.0f);
    float ea = norm * expf(qi * qi);
    float s, c;
    __sincosf(pr * qi, &s, &c);
    float prr = fminf(fmaxf(ea * c, -100.0f), 100.0f);
    float pri = fminf(fmaxf(ea * s, -100.0f), 100.0f);
    float fr = f_re[i], fi = f_im[i];
    vre[i] = prr * fr - pri * fi;           // vals = pref * factors
    vim[i] = prr * fi + pri * fr;
}

// scatter with inline unique-rank scan: wave 0 builds exclusive prefix of
// per-word popcounts (16 words/lane, shfl wave-scan, no barrier ladder).
__global__ void scatter_kernel(const int* __restrict__ bins,
                               const unsigned long long* __restrict__ pres,
                               const float* __restrict__ vre, const float* __restrict__ vim,
                               float* __restrict__ bre, float* __restrict__ bim, int n)
{
    __shared__ int lbase[PRES_WORDS];
    int tid = threadIdx.x;
    if (tid < 64) {
        int cum[16];
        int tot = 0;
        for (int k = 0; k < 16; k++) {
            cum[k] = tot;
            tot += __popcll(pres[tid * 16 + k]);
        }
        int run = tot;
        for (int off = 1; off < 64; off <<= 1) {
            int up = __shfl_up(run, off);
            if (tid >= off) run += up;
        }
        int excl = run - tot;               // exclusive prefix of lane totals
        for (int k = 0; k < 16; k++) lbase[tid * 16 + k] = excl + cum[k];
    }
    __syncthreads();
    int i = blockIdx.x * blockDim.x + tid;
    if (i >= n) return;
    int pidx = min(max(bins[i] + PRES_OFF, 0), PRES_BITS - 1);
    int w = pidx >> 6, bit = pidx & 63;
    unsigned long long below = pres[w] & ((bit == 0) ? 0ull : (~0ull >> (64 - bit)));
    int cid = lbase[w] + __popcll(below);   // rank among sorted unique bins
    atomicAdd(&bre[cid], vre[i]);
    atomicAdd(&bim[cid], vim[i]);
}

// windowed gt: only m with |x[m]-qc| <= ~4.5 contribute above 2e-9.
// x uniform (h=0.01) -> window indices computed, xw gathered from L1.
// blockIdx.y slices each thread's window into CHUNKS; partials non-atomic.
__global__ void gt_kernel(const float2* __restrict__ xw, const float* __restrict__ x,
                          const float* __restrict__ qc, const float* __restrict__ pc,
                          float* __restrict__ gpre, float* __restrict__ gpim,
                          int n, int M)
{
    int t = blockIdx.x * blockDim.x + threadIdx.x;
    if (t >= n) return;
    float qcn = qc[t], pcn = pc[t];
    float x0f = x[0];                        // uniform broadcast load
    float flo = (qcn - WINR - x0f) * 100.0f; // 1/h = 100
    float fhi = (qcn + WINR - x0f) * 100.0f;
    int mlo = max(0, (int)flo - 1);          // +-1 slack absorbs fp rounding
    int mhi = min(M, (int)fhi + 2);
    int len = mhi - mlo; if (len < 0) len = 0;
    int c = blockIdx.y;
    int ms = mlo + (len * c) / CHUNKS;
    int me = mlo + (len * (c + 1)) / CHUNKS;
    float sre = 0.0f, sim = 0.0f;
    for (int m = ms; m < me; m++) {
        float2 xm = xw[m];
        float dxq = xm.x - qcn;
        float e = __expf(-dxq * dxq) * xm.y;
        float s, cc;
        __sincosf(pcn * dxq, &s, &cc);
        sre = fmaf(e, cc, sre);
        sim = fmaf(-e, s, sim);
    }
    gpre[c * n + t] = sre;                   // written exactly once, no zero needed
    gpim[c * n + t] = sim;
}

// per-trajectory chunk-sum + |binned - gt|^2, block reduce, last block sqrts.
__global__ void loss_final_kernel(const float* __restrict__ gpre, const float* __restrict__ gpim,
                                  const float* __restrict__ bre, const float* __restrict__ bim,
                                  float* __restrict__ loss, int* __restrict__ donecnt,
                                  float* __restrict__ out, int n)
{
    int t = blockIdx.x * blockDim.x + threadIdx.x;
    float v = 0.0f;
    if (t < n) {
        float sre = 0.0f, sim = 0.0f;
        for (int c = 0; c < CHUNKS; c++) {
            sre += gpre[c * n + t];
            sim += gpim[c * n + t];
        }
        float dre = bre[t] - sre;
        float dim = bim[t] - sim;
        v = dre * dre + dim * dim;
    }
#pragma unroll
    for (int off = 32; off > 0; off >>= 1) v += __shfl_down(v, off);
    __shared__ float l[4];
    int wv = threadIdx.x >> 6, ln = threadIdx.x & 63;
    if (ln == 0) l[wv] = v;
    __syncthreads();
    if (threadIdx.x == 0) {
        atomicAdd(loss, l[0] + l[1] + l[2] + l[3]);
        __threadfence();
        int old = atomicAdd(donecnt, 1);
        if (old == (int)gridDim.x - 1) {     // last block: all adds visible
            __threadfence();
            out[0] = sqrtf(atomicAdd(loss, 0.0f));
        }
    }
}

extern "C" void kernel_launch(void* const* d_in, const int* in_sizes, int n_in,
                              void* d_out, int out_size, void* d_ws, size_t ws_size,
                              hipStream_t stream)
{
    const float* f_re = (const float*)d_in[0];
    const float* f_im = (const float*)d_in[1];
    const float* q_re = (const float*)d_in[2];
    const float* q_im = (const float*)d_in[3];
    const float* p_re = (const float*)d_in[4];
    const float* p_im = (const float*)d_in[5];
    const float* x    = (const float*)d_in[6];
    const float* psi  = (const float*)d_in[7];
    int n = in_sizes[0];   // 16384
    int M = in_sizes[6];   // ~2401 (fits xw cap 4096)

    // workspace layout (floats unless noted)
    float* wsf  = (float*)d_ws;
    float* qc   = wsf;                       // n
    float* pc   = qc + n;                    // n
    float* vre  = pc + n;                    // n
    float* vim  = vre + n;                   // n
    int*   bins = (int*)(vim + n);           // n
    float* bre  = (float*)(bins + n);        // n
    float* bim  = bre + n;                   // n
    float* gpre = bim + n;                   // CHUNKS*n
    float* gpim = gpre + (size_t)CHUNKS * n; // CHUNKS*n
    float2* xw  = (float2*)(gpim + (size_t)CHUNKS * n); // 4096 float2
    unsigned long long* pres = (unsigned long long*)(xw + 4096); // 1024 u64
    float* loss = (float*)(pres + PRES_WORDS);
    int*   donecnt = (int*)(loss + 1);

    // only pres + loss + donecnt need zeroing (8200 B)
    hipMemsetAsync(pres, 0, PRES_WORDS * sizeof(unsigned long long) + 8, stream);

    int nb = (n + 255) / 256;
    prep_kernel<<<nb, 256, 0, stream>>>(f_re, f_im, q_re, q_im, p_re, p_im, x, psi,
                                        qc, pc, vre, vim, bins, pres, bre, bim, xw, n, M);
    scatter_kernel<<<nb, 256, 0, stream>>>(bins, pres, vre, vim, bre, bim, n);
    gt_kernel<<<dim3(nb, CHUNKS), 256, 0, stream>>>(xw, x, qc, pc, gpre, gpim, n, M);
    loss_final_kernel<<<nb, 256, 0, stream>>>(gpre, gpim, bre, bim, loss, donecnt,
                                              (float*)d_out, n);
}

// Round 4
// 112.642 us; speedup vs baseline: 2.8684x; 1.0482x over previous
//
#include <hip/hip_runtime.h>
#include <math.h>

// CoherentLoss: N=16384 trajectories, grid M ~= 2402 points (x uniform, h=0.01).
// 4 dispatches: memset(8.2KB pres+loss+done) -> prep (bins/centers/prefactor,
// xw table, zero binned) -> gt_scatter (LDS-staged xw, windowed |dxq|<=4.0,
// lane-per-trajectory, chunked over blockIdx.y; y==0 blocks also do the
// unique-rank popcount scan + scatter-add) -> loss reduce (+last-block sqrt).

#define PRES_WORDS 1024          // 65536 bins / 64 bits
#define PRES_BITS  65536
#define PRES_OFF   32768
#define CHUNKS     8
#define MCAP       2432          // >= M, LDS table capacity
#define WINR       4.0f          // exp(-16) = 1.1e-7 -> truncation negligible

__global__ void prep_kernel(const float* __restrict__ f_re, const float* __restrict__ f_im,
                            const float* __restrict__ q_re, const float* __restrict__ q_im,
                            const float* __restrict__ p_re, const float* __restrict__ p_im,
                            const float* __restrict__ x, const float* __restrict__ psi,
                            float* __restrict__ qc, float* __restrict__ pc,
                            float* __restrict__ vre, float* __restrict__ vim,
                            int* __restrict__ bins, unsigned long long* __restrict__ pres,
                            float* __restrict__ bre, float* __restrict__ bim,
                            float2* __restrict__ xw, int n, int M)
{
    int i = blockIdx.x * blockDim.x + threadIdx.x;
    if (i >= n) return;
    bre[i] = 0.0f; bim[i] = 0.0f;           // zero binned accumulators (pre-scatter)
    if (i < M) {                             // folded wpsi: trapz weight * psi * norm
        float w;
        if (i == 0)          w = 0.5f * (x[1] - x[0]);
        else if (i == M - 1) w = 0.5f * (x[M - 1] - x[M - 2]);
        else                 w = 0.5f * (x[i + 1] - x[i - 1]);
        xw[i] = make_float2(x[i], w * psi[i] * 0.8932438417380023f);
    }
    const float norm = 0.8932438417380023f;  // (2/pi)^0.25
    float qi = q_im[i], pr = p_re[i];
    float qf = q_re[i] - 0.5f * p_im[i];     // g = 1, exact pow2 ops
    float pf = 2.0f * qi + pr;
    float qb = floorf((qf - (-8.0f)) / 0.125f);    // dq = 0.125 exact
    float pb = floorf((pf - (-10.0f)) / 0.15625f); // dp = 0.15625 exact
    int b = (int)(qb * 128.0f + pb);
    bins[i] = b;
    int pidx = min(max(b + PRES_OFF, 0), PRES_BITS - 1);
    atomicOr(&pres[pidx >> 6], 1ull << (pidx & 63));
    qc[i] = (qb + 0.5f) * 0.125f + (-8.0f);
    pc[i] = (pb + 0.5f) * 0.15625f + (-10.0f);
    float ea = norm * expf(qi * qi);
    float s, c;
    __sincosf(pr * qi, &s, &c);
    float prr = fminf(fmaxf(ea * c, -100.0f), 100.0f);
    float pri = fminf(fmaxf(ea * s, -100.0f), 100.0f);
    float fr = f_re[i], fi = f_im[i];
    vre[i] = prr * fr - pri * fi;            // vals = pref * factors
    vim[i] = prr * fi + pri * fr;
}

// Fused gt + scatter. All blocks: stage xw into LDS, windowed gt loop
// (lane-per-trajectory, m-window sliced by blockIdx.y). y==0 blocks also
// run the unique-rank scan (wave 0, shfl) and the scatter-add.
__global__ void __launch_bounds__(256) gt_scatter_kernel(
    const float2* __restrict__ xw, const float* __restrict__ x,
    const float* __restrict__ qc, const float* __restrict__ pc,
    const int* __restrict__ bins, const unsigned long long* __restrict__ pres,
    const float* __restrict__ vre, const float* __restrict__ vim,
    float* __restrict__ bre, float* __restrict__ bim,
    float* __restrict__ gpre, float* __restrict__ gpim, int n, int M)
{
    __shared__ float2 sxw[MCAP];             // 19.5 KB
    __shared__ int lbase[PRES_WORDS];        // 4 KB (y==0 only)
    int tid = threadIdx.x;
    for (int m = tid; m < M; m += 256) sxw[m] = xw[m];
    if (blockIdx.y == 0 && tid < 64) {       // exclusive prefix of word popcounts
        int cum[16];
        int tot = 0;
        for (int k = 0; k < 16; k++) { cum[k] = tot; tot += __popcll(pres[tid * 16 + k]); }
        int run = tot;
        for (int off = 1; off < 64; off <<= 1) {
            int up = __shfl_up(run, off);
            if (tid >= off) run += up;
        }
        int excl = run - tot;
        for (int k = 0; k < 16; k++) lbase[tid * 16 + k] = excl + cum[k];
    }
    __syncthreads();
    int t = blockIdx.x * 256 + tid;
    if (t >= n) return;
    if (blockIdx.y == 0) {                   // scatter vals into compact bins
        int pidx = min(max(bins[t] + PRES_OFF, 0), PRES_BITS - 1);
        int w = pidx >> 6, bit = pidx & 63;
        unsigned long long below = pres[w] & ((bit == 0) ? 0ull : (~0ull >> (64 - bit)));
        int cid = lbase[w] + __popcll(below);
        atomicAdd(&bre[cid], vre[t]);
        atomicAdd(&bim[cid], vim[t]);
    }
    float qcn = qc[t], pcn = pc[t];
    float x0f = x[0];                        // uniform broadcast load
    float flo = (qcn - WINR - x0f) * 100.0f; // 1/h = 100
    float fhi = (qcn + WINR - x0f) * 100.0f;
    int mlo = max(0, (int)flo - 1);          // slack absorbs fp rounding
    int mhi = min(M, (int)fhi + 2);
    int len = mhi - mlo; if (len < 0) len = 0;
    int c = blockIdx.y;
    int ms = mlo + (len * c) / CHUNKS;
    int me = mlo + (len * (c + 1)) / CHUNKS;
    float sre = 0.0f, sim = 0.0f;
    for (int m = ms; m < me; m++) {
        float2 xm = sxw[m];                  // LDS gather: ~2 lanes/bank, free
        float dxq = xm.x - qcn;
        float e = __expf(-dxq * dxq) * xm.y;
        float s, cc;
        __sincosf(pcn * dxq, &s, &cc);
        sre = fmaf(e, cc, sre);
        sim = fmaf(-e, s, sim);
    }
    gpre[c * n + t] = sre;                   // written exactly once, no zero needed
    gpim[c * n + t] = sim;
}

// per-trajectory chunk-sum + |binned - gt|^2, block reduce, last block sqrts.
__global__ void loss_final_kernel(const float* __restrict__ gpre, const float* __restrict__ gpim,
                                  const float* __restrict__ bre, const float* __restrict__ bim,
                                  float* __restrict__ loss, int* __restrict__ donecnt,
                                  float* __restrict__ out, int n)
{
    int t = blockIdx.x * blockDim.x + threadIdx.x;
    float v = 0.0f;
    if (t < n) {
        float sre = 0.0f, sim = 0.0f;
        for (int c = 0; c < CHUNKS; c++) {
            sre += gpre[c * n + t];
            sim += gpim[c * n + t];
        }
        float dre = bre[t] - sre;
        float dim = bim[t] - sim;
        v = dre * dre + dim * dim;
    }
#pragma unroll
    for (int off = 32; off > 0; off >>= 1) v += __shfl_down(v, off);
    __shared__ float l[4];
    int wv = threadIdx.x >> 6, ln = threadIdx.x & 63;
    if (ln == 0) l[wv] = v;
    __syncthreads();
    if (threadIdx.x == 0) {
        atomicAdd(loss, l[0] + l[1] + l[2] + l[3]);
        __threadfence();
        int old = atomicAdd(donecnt, 1);
        if (old == (int)gridDim.x - 1) {     // last block: all adds visible
            __threadfence();
            out[0] = sqrtf(atomicAdd(loss, 0.0f));
        }
    }
}

extern "C" void kernel_launch(void* const* d_in, const int* in_sizes, int n_in,
                              void* d_out, int out_size, void* d_ws, size_t ws_size,
                              hipStream_t stream)
{
    const float* f_re = (const float*)d_in[0];
    const float* f_im = (const float*)d_in[1];
    const float* q_re = (const float*)d_in[2];
    const float* q_im = (const float*)d_in[3];
    const float* p_re = (const float*)d_in[4];
    const float* p_im = (const float*)d_in[5];
    const float* x    = (const float*)d_in[6];
    const float* psi  = (const float*)d_in[7];
    int n = in_sizes[0];   // 16384
    int M = in_sizes[6];   // ~2402 (<= MCAP)

    // workspace layout (floats unless noted)
    float* wsf  = (float*)d_ws;
    float* qc   = wsf;                       // n
    float* pc   = qc + n;                    // n
    float* vre  = pc + n;                    // n
    float* vim  = vre + n;                   // n
    int*   bins = (int*)(vim + n);           // n
    float* bre  = (float*)(bins + n);        // n
    float* bim  = bre + n;                   // n
    float* gpre = bim + n;                   // CHUNKS*n
    float* gpim = gpre + (size_t)CHUNKS * n; // CHUNKS*n
    float2* xw  = (float2*)(gpim + (size_t)CHUNKS * n); // MCAP float2
    unsigned long long* pres = (unsigned long long*)(xw + MCAP); // 1024 u64
    float* loss = (float*)(pres + PRES_WORDS);
    int*   donecnt = (int*)(loss + 1);

    // only pres + loss + donecnt need zeroing (8.2 KB)
    hipMemsetAsync(pres, 0, PRES_WORDS * sizeof(unsigned long long) + 8, stream);

    int nb = (n + 255) / 256;
    prep_kernel<<<nb, 256, 0, stream>>>(f_re, f_im, q_re, q_im, p_re, p_im, x, psi,
                                        qc, pc, vre, vim, bins, pres, bre, bim, xw, n, M);
    gt_scatter_kernel<<<dim3(nb, CHUNKS), 256, 0, stream>>>(xw, x, qc, pc, bins, pres,
                                                            vre, vim, bre, bim,
                                                            gpre, gpim, n, M);
    loss_final_kernel<<<nb, 256, 0, stream>>>(gpre, gpim, bre, bim, loss, donecnt,
                                              (float*)d_out, n);
}

// Round 5
// 107.818 us; speedup vs baseline: 2.9967x; 1.0447x over previous
//
#include <hip/hip_runtime.h>
#include <math.h>

// CoherentLoss: N=16384 trajectories, grid M ~= 2402 (x uniform, h=0.01).
// 3 dispatches:
//  K0 memset: pres bitmap + loss + done counters (8.2 KB)
//  K1 gt_kernel: per-thread prep (local qc/pc, y==0 builds pres + zeroes
//     binned), windowed |dxq|<=4 trapz via exp/rot recurrences (no trans in
//     loop), chunked over blockIdx.y, exact-write partials
//  K2 scatter_loss: chunk-sum partials in regs, recompute vals, popcount-rank
//     scatter, in-kernel grid barrier (64 blocks, co-resident), loss + sqrt.

#define PRES_WORDS 1024          // 65536 bins / 64 bits
#define PRES_BITS  65536
#define PRES_OFF   32768
#define CHUNKS     16
#define MCAP       2432          // >= M, LDS wpsi capacity
#define WINR       4.0f          // exp(-16) = 1.1e-7 -> truncation negligible
#define NORM       0.8932438417380023f   // (2/pi)^0.25

__global__ void __launch_bounds__(256) gt_kernel(
    const float* __restrict__ q_re, const float* __restrict__ q_im,
    const float* __restrict__ p_re, const float* __restrict__ p_im,
    const float* __restrict__ x, const float* __restrict__ psi,
    unsigned long long* __restrict__ pres,
    float* __restrict__ bre, float* __restrict__ bim,
    float* __restrict__ gpre, float* __restrict__ gpim, int n, int M)
{
    __shared__ float swpsi[MCAP];            // 9.7 KB: trapz weight * psi * norm
    int tid = threadIdx.x;
    float x0 = x[0];
    float h  = x[1] - x0;                    // uniform step (~0.01)
    for (int m = tid; m < M; m += 256) {
        float w = (m == 0 || m == M - 1) ? 0.5f * h : h;
        swpsi[m] = w * psi[m] * NORM;
    }
    __syncthreads();
    int t = blockIdx.x * 256 + tid;
    if (t >= n) return;
    // local prep: bin centers from this thread's own inputs only
    float qi = q_im[t], pr = p_re[t];
    float qf = q_re[t] - 0.5f * p_im[t];     // g = 1, exact pow2 ops
    float pf = 2.0f * qi + pr;
    float qb = floorf((qf - (-8.0f)) / 0.125f);    // dq exact pow2
    float pb = floorf((pf - (-10.0f)) / 0.15625f); // dp = 5/32 exact
    float qcn = (qb + 0.5f) * 0.125f + (-8.0f);
    float pcn = (pb + 0.5f) * 0.15625f + (-10.0f);
    if (blockIdx.y == 0) {                   // build presence bitmap + zero binned
        int b = (int)(qb * 128.0f + pb);
        int pidx = min(max(b + PRES_OFF, 0), PRES_BITS - 1);
        atomicOr(&pres[pidx >> 6], 1ull << (pidx & 63));
        bre[t] = 0.0f; bim[t] = 0.0f;
    }
    // window [mlo, mhi): |x[m] - qc| <= WINR; x[m] = x0 + m*h
    float inv_h = 1.0f / h;
    int mlo = max(0, (int)((qcn - WINR - x0) * inv_h) - 1);
    int mhi = min(M, (int)((qcn + WINR - x0) * inv_h) + 2);
    int len = mhi - mlo; if (len < 0) len = 0;
    int c = blockIdx.y;
    int ms = mlo + (len * c) / CHUNKS;
    int me = mlo + (len * (c + 1)) / CHUNKS;
    // recurrences: e_m = exp(-dx_m^2) via e*=u, u*=d; (s,c) rotation by pcn*h
    float b0  = x0 - qcn;
    float dx0 = fmaf((float)ms, h, b0);
    float e   = __expf(-dx0 * dx0);
    float u   = __expf(-h * (dx0 + dx0 + h));
    float d   = __expf(-2.0f * h * h);
    float sn, cs, sd, cd;
    __sincosf(pcn * dx0, &sn, &cs);
    __sincosf(pcn * h, &sd, &cd);
    float sre = 0.0f, sim = 0.0f;
    for (int m = ms; m < me; m++) {
        float w = swpsi[m];                  // LDS gather, ~2 lanes/bank: free
        float tv = e * w;
        sre = fmaf(tv, cs, sre);             // integrand: w*e*(cos - i sin)
        sim = fmaf(-tv, sn, sim);
        e *= u; u *= d;                      // exp recurrence
        float cn = fmaf(cs, cd, -sn * sd);   // rotation recurrence
        sn = fmaf(sn, cd, cs * sd);
        cs = cn;
    }
    gpre[c * n + t] = sre;                   // exact write, no zero needed
    gpim[c * n + t] = sim;
}

// 64 blocks (co-resident on 256 CUs): chunk-sum gt in regs, recompute vals,
// rank-scatter into binned, grid barrier, per-slice loss, last block sqrts.
__global__ void __launch_bounds__(256) scatter_loss_kernel(
    const float* __restrict__ f_re, const float* __restrict__ f_im,
    const float* __restrict__ q_re, const float* __restrict__ q_im,
    const float* __restrict__ p_re, const float* __restrict__ p_im,
    const unsigned long long* __restrict__ pres,
    float* __restrict__ bre, float* __restrict__ bim,
    const float* __restrict__ gpre, const float* __restrict__ gpim,
    int* __restrict__ k3done, float* __restrict__ loss, int* __restrict__ fin,
    float* __restrict__ out, int n)
{
    __shared__ int lbase[PRES_WORDS];        // exclusive rank base per 64-bin word
    int tid = threadIdx.x;
    if (tid < 64) {
        int cum[16];
        int tot = 0;
        for (int k = 0; k < 16; k++) { cum[k] = tot; tot += __popcll(pres[tid * 16 + k]); }
        int run = tot;
        for (int off = 1; off < 64; off <<= 1) {
            int up = __shfl_up(run, off);
            if (tid >= off) run += up;
        }
        int excl = run - tot;
        for (int k = 0; k < 16; k++) lbase[tid * 16 + k] = excl + cum[k];
    }
    __syncthreads();
    int t = blockIdx.x * 256 + tid;
    // chunk-sum this thread's gt (stays in registers; no dependency on barrier)
    float sre = 0.0f, sim = 0.0f;
    for (int c = 0; c < CHUNKS; c++) {
        sre += gpre[c * n + t];
        sim += gpim[c * n + t];
    }
    // recompute bin + vals, scatter into compact-rank binned accumulators
    float qi = q_im[t], pr = p_re[t];
    float qf = q_re[t] - 0.5f * p_im[t];
    float pf = 2.0f * qi + pr;
    float qb = floorf((qf - (-8.0f)) / 0.125f);
    float pb = floorf((pf - (-10.0f)) / 0.15625f);
    int b = (int)(qb * 128.0f + pb);
    int pidx = min(max(b + PRES_OFF, 0), PRES_BITS - 1);
    int w = pidx >> 6, bit = pidx & 63;
    unsigned long long below = pres[w] & ((bit == 0) ? 0ull : (~0ull >> (64 - bit)));
    int cid = lbase[w] + __popcll(below);
    float ea = NORM * expf(qi * qi);
    float s, c2;
    __sincosf(pr * qi, &s, &c2);
    float prr = fminf(fmaxf(ea * c2, -100.0f), 100.0f);
    float pri = fminf(fmaxf(ea * s, -100.0f), 100.0f);
    float fr = f_re[t], fi = f_im[t];
    atomicAdd(&bre[cid], prr * fr - pri * fi);
    atomicAdd(&bim[cid], prr * fi + pri * fr);
    // grid barrier: 64 blocks, all co-resident (grid << CU count)
    __threadfence();
    __syncthreads();
    if (tid == 0) {
        __hip_atomic_fetch_add(k3done, 1, __ATOMIC_ACQ_REL, __HIP_MEMORY_SCOPE_AGENT);
        while (__hip_atomic_load(k3done, __ATOMIC_ACQUIRE, __HIP_MEMORY_SCOPE_AGENT)
               < (int)gridDim.x)
            __builtin_amdgcn_s_sleep(4);
    }
    __syncthreads();
    // loss over this block's slice; atomic loads bypass stale L1
    float brt = __hip_atomic_load(&bre[t], __ATOMIC_RELAXED, __HIP_MEMORY_SCOPE_AGENT);
    float bit2 = __hip_atomic_load(&bim[t], __ATOMIC_RELAXED, __HIP_MEMORY_SCOPE_AGENT);
    float dre = brt - sre;
    float dim = bit2 - sim;
    float v = dre * dre + dim * dim;
#pragma unroll
    for (int off = 32; off > 0; off >>= 1) v += __shfl_down(v, off);
    __shared__ float l[4];
    int wv = tid >> 6, ln = tid & 63;
    if (ln == 0) l[wv] = v;
    __syncthreads();
    if (tid == 0) {
        __hip_atomic_fetch_add(loss, l[0] + l[1] + l[2] + l[3],
                               __ATOMIC_ACQ_REL, __HIP_MEMORY_SCOPE_AGENT);
        int old = __hip_atomic_fetch_add(fin, 1, __ATOMIC_ACQ_REL,
                                         __HIP_MEMORY_SCOPE_AGENT);
        if (old == (int)gridDim.x - 1) {     // last block: all adds visible
            out[0] = sqrtf(__hip_atomic_load(loss, __ATOMIC_ACQUIRE,
                                             __HIP_MEMORY_SCOPE_AGENT));
        }
    }
}

extern "C" void kernel_launch(void* const* d_in, const int* in_sizes, int n_in,
                              void* d_out, int out_size, void* d_ws, size_t ws_size,
                              hipStream_t stream)
{
    const float* f_re = (const float*)d_in[0];
    const float* f_im = (const float*)d_in[1];
    const float* q_re = (const float*)d_in[2];
    const float* q_im = (const float*)d_in[3];
    const float* p_re = (const float*)d_in[4];
    const float* p_im = (const float*)d_in[5];
    const float* x    = (const float*)d_in[6];
    const float* psi  = (const float*)d_in[7];
    int n = in_sizes[0];   // 16384
    int M = in_sizes[6];   // ~2402 (<= MCAP)

    // workspace layout
    float* gpre = (float*)d_ws;                         // CHUNKS*n
    float* gpim = gpre + (size_t)CHUNKS * n;            // CHUNKS*n
    float* bre  = gpim + (size_t)CHUNKS * n;            // n
    float* bim  = bre + n;                              // n
    unsigned long long* pres = (unsigned long long*)(bim + n); // 1024 u64
    float* loss    = (float*)(pres + PRES_WORDS);
    int*   k3done  = (int*)(loss + 1);
    int*   fin     = k3done + 1;

    // zero pres + loss + counters (8.2 KB)
    hipMemsetAsync(pres, 0, PRES_WORDS * sizeof(unsigned long long) + 12, stream);

    int nb = (n + 255) / 256;   // 64
    gt_kernel<<<dim3(nb, CHUNKS), 256, 0, stream>>>(q_re, q_im, p_re, p_im, x, psi,
                                                    pres, bre, bim, gpre, gpim, n, M);
    scatter_loss_kernel<<<nb, 256, 0, stream>>>(f_re, f_im, q_re, q_im, p_re, p_im,
                                                pres, bre, bim, gpre, gpim,
                                                k3done, loss, fin, (float*)d_out, n);
}